// Round 1
// baseline (321.296 us; speedup 1.0000x reference)
//
#include <hip/hip_runtime.h>
#include <hip/hip_bf16.h>

// Problem constants
#define BATCH   4096
#define SDIM    512
#define ADIM    64
#define IDIM    577           // 512 + 64 + 1
#define KP      608           // IDIM padded to 19*32
#define NKT     19            // K-tiles of 32
#define HDIM    2048
#define ZDIM    8192          // 4*HDIM

typedef __attribute__((ext_vector_type(8))) __bf16 bf16x8;
typedef __attribute__((ext_vector_type(4))) float  accx4;

// ---------------------------------------------------------------------------
// Kernel 1: prep — build bf16 x=[s|a|r|pad] (4096x608), zh=bh, v_out=bv
// roles by blockIdx: [0,4096) xb rows, [4096,4128) zh init, [4128,4144) v init
// ---------------------------------------------------------------------------
__global__ __launch_bounds__(256) void prep_kernel(
    const float* __restrict__ s, const float* __restrict__ a_prev,
    const float* __restrict__ r_prev, const float* __restrict__ bh,
    const float* __restrict__ bv, __hip_bfloat16* __restrict__ xb,
    float* __restrict__ zh, float* __restrict__ vout)
{
    const int bid = blockIdx.x;
    const int t = threadIdx.x;
    if (bid < BATCH) {
        const float* srow = s + (size_t)bid * SDIM;
        const float* arow = a_prev + (size_t)bid * ADIM;
        __hip_bfloat16* xrow = xb + (size_t)bid * KP;
        for (int c = t; c < KP; c += 256) {
            float v;
            if (c < SDIM)        v = srow[c];
            else if (c < 576)    v = arow[c - SDIM];
            else if (c == 576)   v = r_prev[bid];
            else                 v = 0.0f;          // K padding
            xrow[c] = __float2bfloat16(v);
        }
    } else if (bid < BATCH + 32) {
        int j = (bid - BATCH) * 256 + t;            // 8192 total
        zh[j] = bh[j];
    } else {
        int i = (bid - BATCH - 32) * 256 + t;       // 4096 total
        if (i < BATCH) vout[i] = bv[0];
    }
}

// ---------------------------------------------------------------------------
// Kernel 2: transpose Wx [577,8192] f32 -> WxT [8192,608] bf16 (zero-pad k)
// ---------------------------------------------------------------------------
__global__ __launch_bounds__(256) void transpose_wx(
    const float* __restrict__ wx, __hip_bfloat16* __restrict__ wxt)
{
    __shared__ float tile[32][33];                  // +1 pad breaks conflicts
    const int kt = blockIdx.x;                      // 0..18
    const int nt = blockIdx.y;                      // 0..255
    const int c  = threadIdx.x & 31;
    const int r0 = threadIdx.x >> 5;                // 0..7
#pragma unroll
    for (int i = 0; i < 4; ++i) {
        int r = r0 + i * 8;                         // k within tile
        int k = kt * 32 + r;
        tile[r][c] = (k < IDIM) ? wx[(size_t)k * ZDIM + nt * 32 + c] : 0.0f;
    }
    __syncthreads();
#pragma unroll
    for (int i = 0; i < 4; ++i) {
        int r = r0 + i * 8;                         // n within tile
        wxt[(size_t)(nt * 32 + r) * KP + kt * 32 + c] =
            __float2bfloat16(tile[c][r]);
    }
}

// ---------------------------------------------------------------------------
// Kernel 3: zh[n] += sum_k h[k]*Wh[k][n]   (k split into 16 chunks, atomics)
// ---------------------------------------------------------------------------
__global__ __launch_bounds__(256) void zh_acc(
    const float* __restrict__ h, const float* __restrict__ wh,
    float* __restrict__ zh)
{
    const int n  = blockIdx.x * 256 + threadIdx.x;  // 0..8191
    const int kb = blockIdx.y * 128;
    float p = 0.0f;
    for (int kk = 0; kk < 128; ++kk)
        p = fmaf(h[kb + kk], wh[(size_t)(kb + kk) * ZDIM + n], p);
    atomicAdd(&zh[n], p);
}

// ---------------------------------------------------------------------------
// Kernel 4: main bf16 MFMA GEMM + fused LSTM epilogue
// Block tile: 128 rows x 32 h-units (=> 128 z-cols across 4 gates).
// 4 waves in 2x2: wave = 64 rows x 16 h-units, acc[gate][rowtile] 4x4 f32x4.
// ---------------------------------------------------------------------------
__device__ __forceinline__ float sigmoid_f(float x) {
    return 1.0f / (1.0f + __expf(-x));
}
__device__ __forceinline__ float tanh_f(float x) {
    // tanh(x) = 1 - 2/(exp(2x)+1); saturates correctly at +/-inf
    return 1.0f - 2.0f / (1.0f + __expf(2.0f * x));
}

__global__ __launch_bounds__(256) void lstm_gemm(
    const __hip_bfloat16* __restrict__ xb,   // [4096][608] bf16
    const __hip_bfloat16* __restrict__ wxt,  // [8192][608] bf16 (n-major)
    const float* __restrict__ zh,            // [8192] bias + h@Wh
    const float* __restrict__ cvec,          // [2048]
    const float* __restrict__ wv,            // [2048] value head weights
    float* __restrict__ hout,                // [4096][2048] f32
    float* __restrict__ vout)                // [4096] (pre-init to bv)
{
    __shared__ __bf16 smA[128 * 32];   // [row][k]  8KB
    __shared__ __bf16 smB[128 * 32];   // [zcol][k] 8KB (4 gates x 32 n)
    const int t     = threadIdx.x;
    const int lane  = t & 63;
    const int wid   = t >> 6;          // wave 0..3
    const int m0    = blockIdx.x * 128;
    const int n0    = blockIdx.y * 32;

    accx4 acc[4][4] = {};              // [gate][rowtile]

    const int srow   = lane >> 2;      // staging row within 16-row group
    const int schunk = lane & 3;       // 16B chunk within 64B row

    for (int kt = 0; kt < NKT; ++kt) {
        __syncthreads();               // previous tile fully consumed
        const int kbase = kt * 32 + schunk * 8;
#pragma unroll
        for (int is = 0; is < 2; ++is) {
            const int r = is * 64 + wid * 16 + srow;         // 0..127
            // A tile: rows m0+r
            const __hip_bfloat16* ga = xb + (size_t)(m0 + r) * KP + kbase;
            __bf16* la = smA + (is * 64 + wid * 16) * 32;    // wave-uniform
            __builtin_amdgcn_global_load_lds(
                (const __attribute__((address_space(1))) void*)ga,
                (__attribute__((address_space(3))) void*)la, 16, 0, 0);
            // B tile: gathered WxT rows (gate g, unit n0+nn)
            const int g = r >> 5, nn = r & 31;
            const __hip_bfloat16* gb =
                wxt + (size_t)(g * HDIM + n0 + nn) * KP + kbase;
            __bf16* lb = smB + (is * 64 + wid * 16) * 32;
            __builtin_amdgcn_global_load_lds(
                (const __attribute__((address_space(1))) void*)gb,
                (__attribute__((address_space(3))) void*)lb, 16, 0, 0);
        }
        __syncthreads();               // loads landed

        const int wm = wid >> 1, wn = wid & 1;
        const int koff = (lane >> 4) * 8;
        bf16x8 af[4], bfr[4];
#pragma unroll
        for (int rt = 0; rt < 4; ++rt)
            af[rt] = *(const bf16x8*)(smA +
                (wm * 64 + rt * 16 + (lane & 15)) * 32 + koff);
#pragma unroll
        for (int g = 0; g < 4; ++g)
            bfr[g] = *(const bf16x8*)(smB +
                (g * 32 + wn * 16 + (lane & 15)) * 32 + koff);
#pragma unroll
        for (int g = 0; g < 4; ++g)
#pragma unroll
            for (int rt = 0; rt < 4; ++rt)
                acc[g][rt] = __builtin_amdgcn_mfma_f32_16x16x32_bf16(
                    af[rt], bfr[g], acc[g][rt], 0, 0, 0);
    }

    // Epilogue: gates -> c_new -> h_new; C/D layout col=lane&15,
    // row=(lane>>4)*4+reg (guide §3, HW-verified m89/m91).
    const int wm = wid >> 1, wn = wid & 1;
    const int colg = n0 + wn * 16 + (lane & 15);   // h-unit index
    const float cv  = cvec[colg];
    const float wvv = wv[colg];
    const float zhi = zh[colg];
    const float zhf = zh[HDIM + colg];
    const float zhg = zh[2 * HDIM + colg];
    const float zho = zh[3 * HDIM + colg];
#pragma unroll
    for (int rt = 0; rt < 4; ++rt) {
#pragma unroll
        for (int r = 0; r < 4; ++r) {
            const int row = m0 + wm * 64 + rt * 16 + ((lane >> 4) << 2) + r;
            const float zi = acc[0][rt][r] + zhi;
            const float zf = acc[1][rt][r] + zhf;
            const float zg = acc[2][rt][r] + zhg;
            const float zo = acc[3][rt][r] + zho;
            const float cn = sigmoid_f(zf) * cv + sigmoid_f(zi) * tanh_f(zg);
            const float hn = sigmoid_f(zo) * tanh_f(cn);
            hout[(size_t)row * HDIM + colg] = hn;
            // value-head partial: reduce across the 16 lanes sharing this row
            float vp = hn * wvv;
            vp += __shfl_xor(vp, 1);
            vp += __shfl_xor(vp, 2);
            vp += __shfl_xor(vp, 4);
            vp += __shfl_xor(vp, 8);
            if ((lane & 15) == 0) atomicAdd(&vout[row], vp);
        }
    }
}

// ---------------------------------------------------------------------------
// Kernel 5: policy head — logits = h_new@Wa + ba, softmax over 64 actions.
// Block = 16 rows; wave w owns rows w*4..w*4+3, lane = action. fp32.
// ---------------------------------------------------------------------------
__global__ __launch_bounds__(256) void head_kernel(
    const float* __restrict__ hnew, const float* __restrict__ wa,
    const float* __restrict__ ba, float* __restrict__ probs)
{
    __shared__ float hl[16 * 64];      // 4KB
    __shared__ float wal[64 * 64];     // 16KB
    const int t = threadIdx.x;
    const int a = t & 63;              // action (= lane)
    const int w = t >> 6;              // wave -> row group
    const int r0 = blockIdx.x * 16;
    float accv[4] = {0.f, 0.f, 0.f, 0.f};

    for (int k0 = 0; k0 < HDIM; k0 += 64) {
        __syncthreads();
        {   // stage h_new tile 16x64 (one float4 per thread)
            const int idx = t * 4;
            const int row = idx >> 6, kk = idx & 63;
            *(float4*)(hl + idx) =
                *(const float4*)(hnew + (size_t)(r0 + row) * HDIM + k0 + kk);
        }
#pragma unroll
        for (int i = 0; i < 4; ++i) {  // stage Wa tile 64x64
            const int idx = (t + i * 256) * 4;
            const int kk = idx >> 6, aa = idx & 63;
            *(float4*)(wal + idx) =
                *(const float4*)(wa + (size_t)(k0 + kk) * 64 + aa);
        }
        __syncthreads();
#pragma unroll 8
        for (int kk = 0; kk < 64; ++kk) {
            const float wv_ = wal[kk * 64 + a];
#pragma unroll
            for (int i = 0; i < 4; ++i)
                accv[i] = fmaf(hl[(w * 4 + i) * 64 + kk], wv_, accv[i]);
        }
    }

    const float bav = ba[a];
#pragma unroll
    for (int i = 0; i < 4; ++i) {
        const float logit = accv[i] + bav;
        float m = logit;
#pragma unroll
        for (int mask = 32; mask >= 1; mask >>= 1)
            m = fmaxf(m, __shfl_xor(m, mask));
        const float e = __expf(logit - m);
        float ssum = e;
#pragma unroll
        for (int mask = 32; mask >= 1; mask >>= 1)
            ssum += __shfl_xor(ssum, mask);
        probs[(size_t)(r0 + w * 4 + i) * 64 + a] = e / ssum;
    }
}

// ---------------------------------------------------------------------------
extern "C" void kernel_launch(void* const* d_in, const int* in_sizes, int n_in,
                              void* d_out, int out_size, void* d_ws,
                              size_t ws_size, hipStream_t stream)
{
    const float* s      = (const float*)d_in[0];
    const float* a_prev = (const float*)d_in[1];
    const float* r_prev = (const float*)d_in[2];
    const float* h      = (const float*)d_in[3];
    const float* c      = (const float*)d_in[4];
    const float* Wx     = (const float*)d_in[5];
    const float* Wh     = (const float*)d_in[6];
    const float* bh     = (const float*)d_in[7];
    const float* Wa     = (const float*)d_in[8];
    const float* ba     = (const float*)d_in[9];
    const float* Wv     = (const float*)d_in[10];
    const float* bv     = (const float*)d_in[11];

    float* out   = (float*)d_out;
    float* probs = out;                       // [4096*64]
    float* vout  = out + (size_t)BATCH * ADIM; // [4096]

    // Workspace layout (all 16B-aligned)
    char* ws = (char*)d_ws;
    __hip_bfloat16* xb  = (__hip_bfloat16*)ws;                    // 4.98 MB
    __hip_bfloat16* wxt = (__hip_bfloat16*)(ws + 4980736);        // 9.96 MB
    float* zh           = (float*)(ws + 14942208);                // 32 KB
    float* hnew         = (float*)(ws + 14974976);                // 33.5 MB
    // total 48,529,408 bytes

    prep_kernel<<<BATCH + 32 + 16, 256, 0, stream>>>(
        s, a_prev, r_prev, bh, bv, xb, zh, vout);
    transpose_wx<<<dim3(NKT, 256), 256, 0, stream>>>(Wx, wxt);
    zh_acc<<<dim3(32, 16), 256, 0, stream>>>(h, Wh, zh);
    lstm_gemm<<<dim3(BATCH / 128, HDIM / 32), 256, 0, stream>>>(
        xb, wxt, zh, c, Wv, hnew, vout);
    head_kernel<<<BATCH / 16, 256, 0, stream>>>(hnew, Wa, ba, probs);
}

// Round 2
// 241.590 us; speedup vs baseline: 1.3299x; 1.3299x over previous
//
#include <hip/hip_runtime.h>
#include <hip/hip_bf16.h>

// Problem constants
#define BATCH   4096
#define SDIM    512
#define ADIM    64
#define IDIM    577           // 512 + 64 + 1
#define KP      608           // IDIM padded to 19*32
#define NKT     19            // K-tiles of 32
#define HDIM    2048
#define ZDIM    8192          // 4*HDIM

typedef __attribute__((ext_vector_type(8))) __bf16 bf16x8;
typedef __attribute__((ext_vector_type(4))) float  accx4;

// ---------------------------------------------------------------------------
// Kernel 1: prep — build bf16 x=[s|a|r|pad] (4096x608), zh=bh, v_out=bv
// ---------------------------------------------------------------------------
__global__ __launch_bounds__(256) void prep_kernel(
    const float* __restrict__ s, const float* __restrict__ a_prev,
    const float* __restrict__ r_prev, const float* __restrict__ bh,
    const float* __restrict__ bv, __hip_bfloat16* __restrict__ xb,
    float* __restrict__ zh, float* __restrict__ vout)
{
    const int bid = blockIdx.x;
    const int t = threadIdx.x;
    if (bid < BATCH) {
        const float* srow = s + (size_t)bid * SDIM;
        const float* arow = a_prev + (size_t)bid * ADIM;
        __hip_bfloat16* xrow = xb + (size_t)bid * KP;
        for (int c = t; c < KP; c += 256) {
            float v;
            if (c < SDIM)        v = srow[c];
            else if (c < 576)    v = arow[c - SDIM];
            else if (c == 576)   v = r_prev[bid];
            else                 v = 0.0f;          // K padding
            xrow[c] = __float2bfloat16(v);
        }
    } else if (bid < BATCH + 32) {
        int j = (bid - BATCH) * 256 + t;            // 8192 total
        zh[j] = bh[j];
    } else {
        int i = (bid - BATCH - 32) * 256 + t;       // 4096 total
        if (i < BATCH) vout[i] = bv[0];
    }
}

// ---------------------------------------------------------------------------
// Kernel 2: transpose Wx [577,8192] f32 -> WxT [8192,608] bf16 (zero-pad k)
// ---------------------------------------------------------------------------
__global__ __launch_bounds__(256) void transpose_wx(
    const float* __restrict__ wx, __hip_bfloat16* __restrict__ wxt)
{
    __shared__ float tile[32][33];                  // +1 pad breaks conflicts
    const int kt = blockIdx.x;                      // 0..18
    const int nt = blockIdx.y;                      // 0..255
    const int c  = threadIdx.x & 31;
    const int r0 = threadIdx.x >> 5;                // 0..7
#pragma unroll
    for (int i = 0; i < 4; ++i) {
        int r = r0 + i * 8;                         // k within tile
        int k = kt * 32 + r;
        tile[r][c] = (k < IDIM) ? wx[(size_t)k * ZDIM + nt * 32 + c] : 0.0f;
    }
    __syncthreads();
#pragma unroll
    for (int i = 0; i < 4; ++i) {
        int r = r0 + i * 8;                         // n within tile
        wxt[(size_t)(nt * 32 + r) * KP + kt * 32 + c] =
            __float2bfloat16(tile[c][r]);
    }
}

// ---------------------------------------------------------------------------
// Kernel 2b: transpose Wa [2048,64] f32 -> WaT [64,2048] bf16 (action-major)
// ---------------------------------------------------------------------------
__global__ __launch_bounds__(256) void transpose_wa(
    const float* __restrict__ wa, __hip_bfloat16* __restrict__ waT)
{
    __shared__ float tile[32][33];
    const int kt = blockIdx.x;                      // 0..63 (k tiles)
    const int at = blockIdx.y;                      // 0..1  (action tiles)
    const int c  = threadIdx.x & 31;
    const int r0 = threadIdx.x >> 5;                // 0..7
#pragma unroll
    for (int i = 0; i < 4; ++i) {
        int r = r0 + i * 8;                         // k within tile
        tile[r][c] = wa[(size_t)(kt * 32 + r) * ADIM + at * 32 + c];
    }
    __syncthreads();
#pragma unroll
    for (int i = 0; i < 4; ++i) {
        int r = r0 + i * 8;                         // action within tile
        waT[(size_t)(at * 32 + r) * HDIM + kt * 32 + c] =
            __float2bfloat16(tile[c][r]);
    }
}

// ---------------------------------------------------------------------------
// Kernel 3: zh[n] += sum_k h[k]*Wh[k][n]   (k split into 16 chunks, atomics)
// ---------------------------------------------------------------------------
__global__ __launch_bounds__(256) void zh_acc(
    const float* __restrict__ h, const float* __restrict__ wh,
    float* __restrict__ zh)
{
    const int n  = blockIdx.x * 256 + threadIdx.x;  // 0..8191
    const int kb = blockIdx.y * 128;
    float p = 0.0f;
    for (int kk = 0; kk < 128; ++kk)
        p = fmaf(h[kb + kk], wh[(size_t)(kb + kk) * ZDIM + n], p);
    atomicAdd(&zh[n], p);
}

// ---------------------------------------------------------------------------
// Kernel 4: main bf16 MFMA GEMM + fused LSTM epilogue
// Block tile: 128 rows x 32 h-units (=> 128 z-cols across 4 gates).
// 4 waves in 2x2: wave = 64 rows x 16 h-units, acc[gate][rowtile] 4x4 f32x4.
// ---------------------------------------------------------------------------
__device__ __forceinline__ float sigmoid_f(float x) {
    return 1.0f / (1.0f + __expf(-x));
}
__device__ __forceinline__ float tanh_f(float x) {
    // tanh(x) = 1 - 2/(exp(2x)+1); saturates correctly at +/-inf
    return 1.0f - 2.0f / (1.0f + __expf(2.0f * x));
}

__global__ __launch_bounds__(256) void lstm_gemm(
    const __hip_bfloat16* __restrict__ xb,   // [4096][608] bf16
    const __hip_bfloat16* __restrict__ wxt,  // [8192][608] bf16 (n-major)
    const float* __restrict__ zh,            // [8192] bias + h@Wh
    const float* __restrict__ cvec,          // [2048]
    const float* __restrict__ wv,            // [2048] value head weights
    __hip_bfloat16* __restrict__ hout,       // [4096][2048] bf16
    float* __restrict__ vout)                // [4096] (pre-init to bv)
{
    __shared__ __bf16 smA[128 * 32];   // [row][k]  8KB
    __shared__ __bf16 smB[128 * 32];   // [zcol][k] 8KB (4 gates x 32 n)
    const int t     = threadIdx.x;
    const int lane  = t & 63;
    const int wid   = t >> 6;          // wave 0..3
    const int m0    = blockIdx.x * 128;
    const int n0    = blockIdx.y * 32;

    accx4 acc[4][4] = {};              // [gate][rowtile]

    const int srow   = lane >> 2;      // staging row within 16-row group
    const int schunk = lane & 3;       // 16B chunk within 64B row

    for (int kt = 0; kt < NKT; ++kt) {
        __syncthreads();               // previous tile fully consumed
        const int kbase = kt * 32 + schunk * 8;
#pragma unroll
        for (int is = 0; is < 2; ++is) {
            const int r = is * 64 + wid * 16 + srow;         // 0..127
            // A tile: rows m0+r
            const __hip_bfloat16* ga = xb + (size_t)(m0 + r) * KP + kbase;
            __bf16* la = smA + (is * 64 + wid * 16) * 32;    // wave-uniform
            __builtin_amdgcn_global_load_lds(
                (const __attribute__((address_space(1))) void*)ga,
                (__attribute__((address_space(3))) void*)la, 16, 0, 0);
            // B tile: gathered WxT rows (gate g, unit n0+nn)
            const int g = r >> 5, nn = r & 31;
            const __hip_bfloat16* gb =
                wxt + (size_t)(g * HDIM + n0 + nn) * KP + kbase;
            __bf16* lb = smB + (is * 64 + wid * 16) * 32;
            __builtin_amdgcn_global_load_lds(
                (const __attribute__((address_space(1))) void*)gb,
                (__attribute__((address_space(3))) void*)lb, 16, 0, 0);
        }
        __syncthreads();               // loads landed

        const int wm = wid >> 1, wn = wid & 1;
        const int koff = (lane >> 4) * 8;
        bf16x8 af[4], bfr[4];
#pragma unroll
        for (int rt = 0; rt < 4; ++rt)
            af[rt] = *(const bf16x8*)(smA +
                (wm * 64 + rt * 16 + (lane & 15)) * 32 + koff);
#pragma unroll
        for (int g = 0; g < 4; ++g)
            bfr[g] = *(const bf16x8*)(smB +
                (g * 32 + wn * 16 + (lane & 15)) * 32 + koff);
#pragma unroll
        for (int g = 0; g < 4; ++g)
#pragma unroll
            for (int rt = 0; rt < 4; ++rt)
                acc[g][rt] = __builtin_amdgcn_mfma_f32_16x16x32_bf16(
                    af[rt], bfr[g], acc[g][rt], 0, 0, 0);
    }

    // Epilogue: gates -> c_new -> h_new; C/D layout col=lane&15,
    // row=(lane>>4)*4+reg (guide §3, HW-verified m89/m91).
    const int wm = wid >> 1, wn = wid & 1;
    const int colg = n0 + wn * 16 + (lane & 15);   // h-unit index
    const float cv  = cvec[colg];
    const float wvv = wv[colg];
    const float zhi = zh[colg];
    const float zhf = zh[HDIM + colg];
    const float zhg = zh[2 * HDIM + colg];
    const float zho = zh[3 * HDIM + colg];
#pragma unroll
    for (int rt = 0; rt < 4; ++rt) {
#pragma unroll
        for (int r = 0; r < 4; ++r) {
            const int row = m0 + wm * 64 + rt * 16 + ((lane >> 4) << 2) + r;
            const float zi = acc[0][rt][r] + zhi;
            const float zf = acc[1][rt][r] + zhf;
            const float zg = acc[2][rt][r] + zhg;
            const float zo = acc[3][rt][r] + zho;
            const float cn = sigmoid_f(zf) * cv + sigmoid_f(zi) * tanh_f(zg);
            const float hn = sigmoid_f(zo) * tanh_f(cn);
            hout[(size_t)row * HDIM + colg] = __float2bfloat16(hn);
            // value-head partial: reduce across the 16 lanes sharing this row
            float vp = hn * wvv;
            vp += __shfl_xor(vp, 1);
            vp += __shfl_xor(vp, 2);
            vp += __shfl_xor(vp, 4);
            vp += __shfl_xor(vp, 8);
            if ((lane & 15) == 0) atomicAdd(&vout[row], vp);
        }
    }
}

// ---------------------------------------------------------------------------
// Kernel 5: policy head — MFMA logits (bf16 in, fp32 acc) + fused softmax.
// Block = 16 rows x 64 actions; 4 waves, wave w owns action tile w*16..+15.
// A-frags and B-frags loaded DIRECTLY from global (no LDS GEMM staging):
//   A: lanes {l,l+16,l+32,l+48} cover one 64B line of one h_new row.
//   B: WaT [64][2048] bf16 rows, L2-resident (256 KB shared by all blocks).
// ---------------------------------------------------------------------------
__global__ __launch_bounds__(256) void head_kernel(
    const __hip_bfloat16* __restrict__ hnew,  // [4096][2048] bf16
    const __hip_bfloat16* __restrict__ waT,   // [64][2048] bf16
    const float* __restrict__ ba, float* __restrict__ probs)
{
    __shared__ float lg[16][68];              // logits exchange, padded
    const int t    = threadIdx.x;
    const int lane = t & 63;
    const int wid  = t >> 6;
    const int r0   = blockIdx.x * 16;

    const __bf16* arow = (const __bf16*)hnew +
        (size_t)(r0 + (lane & 15)) * HDIM + (lane >> 4) * 8;
    const __bf16* brow = (const __bf16*)waT +
        (size_t)(wid * 16 + (lane & 15)) * HDIM + (lane >> 4) * 8;

    accx4 acc = {};
#pragma unroll 8
    for (int kk = 0; kk < HDIM; kk += 32) {
        bf16x8 af = *(const bf16x8*)(arow + kk);
        bf16x8 bf = *(const bf16x8*)(brow + kk);
        acc = __builtin_amdgcn_mfma_f32_16x16x32_bf16(af, bf, acc, 0, 0, 0);
    }
    // C/D layout: col(action-in-tile)=lane&15, row=(lane>>4)*4+reg
#pragma unroll
    for (int r = 0; r < 4; ++r)
        lg[(lane >> 4) * 4 + r][wid * 16 + (lane & 15)] = acc[r];
    __syncthreads();

    // softmax: wave wid owns rows wid*4..+3; lane = action (64 = wave width)
    const float bav = ba[lane];
#pragma unroll
    for (int i = 0; i < 4; ++i) {
        const int row = wid * 4 + i;
        const float logit = lg[row][lane] + bav;
        float m = logit;
#pragma unroll
        for (int mask = 32; mask >= 1; mask >>= 1)
            m = fmaxf(m, __shfl_xor(m, mask));
        const float e = __expf(logit - m);
        float ssum = e;
#pragma unroll
        for (int mask = 32; mask >= 1; mask >>= 1)
            ssum += __shfl_xor(ssum, mask);
        probs[(size_t)(r0 + row) * 64 + lane] = e / ssum;
    }
}

// ---------------------------------------------------------------------------
extern "C" void kernel_launch(void* const* d_in, const int* in_sizes, int n_in,
                              void* d_out, int out_size, void* d_ws,
                              size_t ws_size, hipStream_t stream)
{
    const float* s      = (const float*)d_in[0];
    const float* a_prev = (const float*)d_in[1];
    const float* r_prev = (const float*)d_in[2];
    const float* h      = (const float*)d_in[3];
    const float* c      = (const float*)d_in[4];
    const float* Wx     = (const float*)d_in[5];
    const float* Wh     = (const float*)d_in[6];
    const float* bh     = (const float*)d_in[7];
    const float* Wa     = (const float*)d_in[8];
    const float* ba     = (const float*)d_in[9];
    const float* Wv     = (const float*)d_in[10];
    const float* bv     = (const float*)d_in[11];

    float* out   = (float*)d_out;
    float* probs = out;                        // [4096*64]
    float* vout  = out + (size_t)BATCH * ADIM; // [4096]

    // Workspace layout (all 16B-aligned)
    char* ws = (char*)d_ws;
    __hip_bfloat16* xb   = (__hip_bfloat16*)ws;                 // 4,980,736 B
    __hip_bfloat16* wxt  = (__hip_bfloat16*)(ws + 4980736);     // 9,961,472 B
    float* zh            = (float*)(ws + 14942208);             //    32,768 B
    __hip_bfloat16* hnew = (__hip_bfloat16*)(ws + 14974976);    // 16,777,216 B
    __hip_bfloat16* waT  = (__hip_bfloat16*)(ws + 31752192);    //   262,144 B
    // total 32,014,336 bytes

    prep_kernel<<<BATCH + 32 + 16, 256, 0, stream>>>(
        s, a_prev, r_prev, bh, bv, xb, zh, vout);
    transpose_wx<<<dim3(NKT, 256), 256, 0, stream>>>(Wx, wxt);
    transpose_wa<<<dim3(HDIM / 32, ADIM / 32), 256, 0, stream>>>(Wa, waT);
    zh_acc<<<dim3(32, 16), 256, 0, stream>>>(h, Wh, zh);
    lstm_gemm<<<dim3(BATCH / 128, HDIM / 32), 256, 0, stream>>>(
        xb, wxt, zh, c, Wv, hnew, vout);
    head_kernel<<<BATCH / 16, 256, 0, stream>>>(hnew, waT, ba, probs);
}

// Round 3
// 235.810 us; speedup vs baseline: 1.3625x; 1.0245x over previous
//
#include <hip/hip_runtime.h>
#include <hip/hip_bf16.h>

// Problem constants
#define BATCH   4096
#define SDIM    512
#define ADIM    64
#define IDIM    577           // 512 + 64 + 1
#define KP2     640           // IDIM padded to 10*64
#define NKT2    10            // K-tiles of 64
#define HDIM    2048
#define ZDIM    8192          // 4*HDIM

typedef __attribute__((ext_vector_type(8))) __bf16 bf16x8;
typedef __attribute__((ext_vector_type(4))) float  accx4;

// ---------------------------------------------------------------------------
// Fused setup kernel. Role by flat blockIdx (all roles independent):
//   [0,2560)        transpose Wx [577,8192]f32 -> wxt [8192][640]bf16
//   [2560,2816)     zh partials: zh_w[ky][n] = sum_{k in ky*256..+256} h*Wh
//   [2816,6912)     prep xb rows: bf16 [s|a|r|0pad] (4096 x 640)
//   [6912,7040)     transpose Wa [2048,64]f32 -> waT [64][2048]bf16
// ---------------------------------------------------------------------------
__global__ __launch_bounds__(256) void setup_kernel(
    const float* __restrict__ s, const float* __restrict__ a_prev,
    const float* __restrict__ r_prev, const float* __restrict__ h,
    const float* __restrict__ wx, const float* __restrict__ wh,
    const float* __restrict__ wa,
    __hip_bfloat16* __restrict__ xb, __hip_bfloat16* __restrict__ wxt,
    __hip_bfloat16* __restrict__ waT, float* __restrict__ zh_w)
{
    __shared__ float stile[64 * 33];
    const int bid = blockIdx.x;
    const int t = threadIdx.x;

    if (bid < 2560) {                       // ---- transpose Wx (64k x 32n)
        const int kt2 = bid >> 8;           // 0..9
        const int nt  = bid & 255;          // 0..255
        const int c  = t & 31, r0 = t >> 5;
#pragma unroll
        for (int i = 0; i < 8; ++i) {
            int r = r0 + i * 8;             // k within tile
            int k = kt2 * 64 + r;
            stile[r * 33 + c] =
                (k < IDIM) ? wx[(size_t)k * ZDIM + nt * 32 + c] : 0.0f;
        }
        __syncthreads();
        const int nr = t >> 3, ch = t & 7;
        bf16x8 w8;
#pragma unroll
        for (int j = 0; j < 8; ++j)
            w8[j] = (__bf16)stile[(ch * 8 + j) * 33 + nr];
        *(bf16x8*)(wxt + (size_t)(nt * 32 + nr) * KP2 + kt2 * 64 + ch * 8) = w8;
    } else if (bid < 2816) {                // ---- zh partials
        const int zb = bid - 2560;
        const int nb = zb & 31, ky = zb >> 5;
        const int n  = nb * 256 + t;
        const float* hp  = h + ky * 256;
        const float* whp = wh + (size_t)ky * 256 * ZDIM + n;
        float p = 0.0f;
#pragma unroll 8
        for (int kk = 0; kk < 256; ++kk)
            p = fmaf(hp[kk], whp[(size_t)kk * ZDIM], p);
        zh_w[ky * ZDIM + n] = p;
    } else if (bid < 6912) {                // ---- prep xb row
        const int row = bid - 2816;
        const float* srow = s + (size_t)row * SDIM;
        const float* arow = a_prev + (size_t)row * ADIM;
        __hip_bfloat16* xrow = xb + (size_t)row * KP2;
        for (int c = t; c < KP2; c += 256) {
            float v;
            if (c < SDIM)        v = srow[c];
            else if (c < 576)    v = arow[c - SDIM];
            else if (c == 576)   v = r_prev[row];
            else                 v = 0.0f;
            xrow[c] = __float2bfloat16(v);
        }
    } else {                                // ---- transpose Wa (32k x 32a)
        const int wb = bid - 6912;
        const int kt = wb >> 1, at = wb & 1;
        const int c  = t & 31, r0 = t >> 5;
#pragma unroll
        for (int i = 0; i < 4; ++i) {
            int r = r0 + i * 8;             // k within tile
            stile[r * 33 + c] = wa[(size_t)(kt * 32 + r) * ADIM + at * 32 + c];
        }
        __syncthreads();
#pragma unroll
        for (int i = 0; i < 4; ++i) {
            int r = r0 + i * 8;             // action within tile
            waT[(size_t)(at * 32 + r) * HDIM + kt * 32 + c] =
                __float2bfloat16(stile[c * 33 + r]);
        }
    }
}

// ---------------------------------------------------------------------------
// Main bf16 MFMA GEMM + fused LSTM epilogue.
// Block tile: 128 rows x 32 h-units (128 z-cols over 4 gates), BK=64.
// LDS rows are 64 elems (128B), 16B chunks XOR-swizzled: slot = chunk^(row&7)
// so staging (base+lane*16) and fragment reads are both bank-conflict-free.
// ---------------------------------------------------------------------------
__device__ __forceinline__ float sigmoid_f(float x) {
    return 1.0f / (1.0f + __expf(-x));
}
__device__ __forceinline__ float tanh_f(float x) {
    return 1.0f - 2.0f / (1.0f + __expf(2.0f * x));
}

__global__ __launch_bounds__(256) void lstm_gemm(
    const __hip_bfloat16* __restrict__ xb,   // [4096][640] bf16
    const __hip_bfloat16* __restrict__ wxt,  // [8192][640] bf16 (n-major)
    const float* __restrict__ zh_w,          // [8][8192] k-split partials
    const float* __restrict__ bh,            // [8192]
    const float* __restrict__ cvec,          // [2048]
    __hip_bfloat16* __restrict__ hout)       // [4096][2048] bf16
{
    __shared__ __bf16 smA[128 * 64];   // 16KB  [row][k-chunk swizzled]
    __shared__ __bf16 smB[128 * 64];   // 16KB  [zcol][k-chunk swizzled]
    const int t    = threadIdx.x;
    const int lane = t & 63;
    const int wid  = t >> 6;
    const int m0   = blockIdx.x * 128;
    const int n0   = blockIdx.y * 32;

    accx4 acc[4][4] = {};              // [gate][rowtile]

    const int srow = lane >> 3;        // row within 8-row staging group
    const int slot = lane & 7;         // 16B slot this lane fills
    const int wm = wid >> 1, wn = wid & 1;
    const int fl15 = lane & 15;
    const int fhi  = lane >> 4;        // 0..3 (k-chunk within 32-k half)

    for (int kt = 0; kt < NKT2; ++kt) {
        __syncthreads();               // previous tile fully consumed
#pragma unroll
        for (int i = 0; i < 4; ++i) {
            const int r = wid * 32 + i * 8 + srow;           // 0..127
            const int c = slot ^ (r & 7);                    // global chunk
            const __hip_bfloat16* ga =
                xb + (size_t)(m0 + r) * KP2 + kt * 64 + c * 8;
            __bf16* la = smA + (wid * 32 + i * 8) * 64;      // wave-uniform
            __builtin_amdgcn_global_load_lds(
                (const __attribute__((address_space(1))) void*)ga,
                (__attribute__((address_space(3))) void*)la, 16, 0, 0);
            const int g = r >> 5, nn = r & 31;
            const __hip_bfloat16* gb =
                wxt + (size_t)(g * HDIM + n0 + nn) * KP2 + kt * 64 + c * 8;
            __bf16* lb = smB + (wid * 32 + i * 8) * 64;
            __builtin_amdgcn_global_load_lds(
                (const __attribute__((address_space(1))) void*)gb,
                (__attribute__((address_space(3))) void*)lb, 16, 0, 0);
        }
        __syncthreads();               // loads landed

#pragma unroll
        for (int hf = 0; hf < 2; ++hf) {
            const int ck = hf * 4 + fhi;          // wanted k-chunk
            const int sl = (ck ^ (lane & 7)) * 8; // swizzled elem offset
            bf16x8 af[4], bfr[4];
#pragma unroll
            for (int rt = 0; rt < 4; ++rt)
                af[rt] = *(const bf16x8*)(smA +
                    (wm * 64 + rt * 16 + fl15) * 64 + sl);
#pragma unroll
            for (int g = 0; g < 4; ++g)
                bfr[g] = *(const bf16x8*)(smB +
                    (g * 32 + wn * 16 + fl15) * 64 + sl);
#pragma unroll
            for (int g = 0; g < 4; ++g)
#pragma unroll
                for (int rt = 0; rt < 4; ++rt)
                    acc[g][rt] = __builtin_amdgcn_mfma_f32_16x16x32_bf16(
                        af[rt], bfr[g], acc[g][rt], 0, 0, 0);
        }
    }

    // Epilogue. C/D layout: col=lane&15, row=(lane>>4)*4+reg (m89/m91).
    const int colg = n0 + wn * 16 + fl15;        // h-unit index
    float zsum[4];
#pragma unroll
    for (int g = 0; g < 4; ++g) {
        float v = bh[g * HDIM + colg];
#pragma unroll
        for (int j = 0; j < 8; ++j)
            v += zh_w[j * ZDIM + g * HDIM + colg];
        zsum[g] = v;
    }
    const float cv = cvec[colg];
#pragma unroll
    for (int rt = 0; rt < 4; ++rt) {
#pragma unroll
        for (int r = 0; r < 4; ++r) {
            const int row = m0 + wm * 64 + rt * 16 + (fhi << 2) + r;
            const float zi = acc[0][rt][r] + zsum[0];
            const float zf = acc[1][rt][r] + zsum[1];
            const float zg = acc[2][rt][r] + zsum[2];
            const float zo = acc[3][rt][r] + zsum[3];
            const float cn = sigmoid_f(zf) * cv + sigmoid_f(zi) * tanh_f(zg);
            const float hn = sigmoid_f(zo) * tanh_f(cn);
            hout[(size_t)row * HDIM + colg] = __float2bfloat16(hn);
        }
    }
}

// ---------------------------------------------------------------------------
// Policy+value head: logits = hnew@Wa + ba (MFMA, K split over 2 wave-groups,
// dual accumulators), fused softmax; v = hnew@Wv + bv (fp32 Wv, 2 waves).
// 512 threads: wave = (kh = wid>>2, action-tile = wid&3). Block = 16 rows.
// ---------------------------------------------------------------------------
__global__ __launch_bounds__(512) void head_kernel(
    const __hip_bfloat16* __restrict__ hnew,  // [4096][2048] bf16
    const __hip_bfloat16* __restrict__ waT,   // [64][2048] bf16
    const float* __restrict__ wv,             // [2048] f32
    const float* __restrict__ ba, const float* __restrict__ bv,
    float* __restrict__ probs, float* __restrict__ vout)
{
    __shared__ float lg[2][16][68];
    __shared__ float vpart[2][16];
    const int t    = threadIdx.x;
    const int lane = t & 63;
    const int wid  = t >> 6;           // 0..7
    const int kh   = wid >> 2;         // k half
    const int wid2 = wid & 3;          // action tile
    const int r0   = blockIdx.x * 16;
    const int fl15 = lane & 15, fhi = lane >> 4;

    const __bf16* arow = (const __bf16*)hnew +
        (size_t)(r0 + fl15) * HDIM + kh * 1024 + fhi * 8;
    const __bf16* brow = (const __bf16*)waT +
        (size_t)(wid2 * 16 + fl15) * HDIM + kh * 1024 + fhi * 8;
    const float* wvp = wv + kh * 1024 + fhi * 8;
    const bool do_v = (wid2 == 0);

    accx4 acc0 = {}, acc1 = {};
    float vacc = 0.0f;
#pragma unroll 4
    for (int kk = 0; kk < 1024; kk += 64) {
        bf16x8 a0 = *(const bf16x8*)(arow + kk);
        bf16x8 b0 = *(const bf16x8*)(brow + kk);
        bf16x8 a1 = *(const bf16x8*)(arow + kk + 32);
        bf16x8 b1 = *(const bf16x8*)(brow + kk + 32);
        acc0 = __builtin_amdgcn_mfma_f32_16x16x32_bf16(a0, b0, acc0, 0, 0, 0);
        acc1 = __builtin_amdgcn_mfma_f32_16x16x32_bf16(a1, b1, acc1, 0, 0, 0);
        if (do_v) {
#pragma unroll
            for (int j = 0; j < 8; ++j) {
                vacc = fmaf((float)a0[j], wvp[kk + j], vacc);
                vacc = fmaf((float)a1[j], wvp[kk + 32 + j], vacc);
            }
        }
    }
    // C/D layout: col(action-in-tile)=lane&15, row=(lane>>4)*4+reg
#pragma unroll
    for (int r = 0; r < 4; ++r)
        lg[kh][fhi * 4 + r][wid2 * 16 + fl15] = acc0[r] + acc1[r];
    if (do_v) {
        vacc += __shfl_xor(vacc, 16);
        vacc += __shfl_xor(vacc, 32);
        if (lane < 16) vpart[kh][lane] = vacc;
    }
    __syncthreads();

    // softmax: 8 waves x 2 rows; lane = action (wave width 64 = ADIM)
    const float bav = ba[lane];
#pragma unroll
    for (int i = 0; i < 2; ++i) {
        const int row = wid * 2 + i;
        const float logit = lg[0][row][lane] + lg[1][row][lane] + bav;
        float m = logit;
#pragma unroll
        for (int mask = 32; mask >= 1; mask >>= 1)
            m = fmaxf(m, __shfl_xor(m, mask));
        const float e = __expf(logit - m);
        float ssum = e;
#pragma unroll
        for (int mask = 32; mask >= 1; mask >>= 1)
            ssum += __shfl_xor(ssum, mask);
        probs[(size_t)(r0 + row) * 64 + lane] = e / ssum;
    }
    if (t < 16) vout[r0 + t] = vpart[0][t] + vpart[1][t] + bv[0];
}

// ---------------------------------------------------------------------------
extern "C" void kernel_launch(void* const* d_in, const int* in_sizes, int n_in,
                              void* d_out, int out_size, void* d_ws,
                              size_t ws_size, hipStream_t stream)
{
    const float* s      = (const float*)d_in[0];
    const float* a_prev = (const float*)d_in[1];
    const float* r_prev = (const float*)d_in[2];
    const float* h      = (const float*)d_in[3];
    const float* c      = (const float*)d_in[4];
    const float* Wx     = (const float*)d_in[5];
    const float* Wh     = (const float*)d_in[6];
    const float* bh     = (const float*)d_in[7];
    const float* Wa     = (const float*)d_in[8];
    const float* ba     = (const float*)d_in[9];
    const float* Wv     = (const float*)d_in[10];
    const float* bv     = (const float*)d_in[11];

    float* out   = (float*)d_out;
    float* probs = out;                        // [4096*64]
    float* vout  = out + (size_t)BATCH * ADIM; // [4096]

    // Workspace layout (16B-aligned)
    char* ws = (char*)d_ws;
    __hip_bfloat16* xb   = (__hip_bfloat16*)ws;                 //  5,242,880
    __hip_bfloat16* wxt  = (__hip_bfloat16*)(ws + 5242880);     // 10,485,760
    __hip_bfloat16* waT  = (__hip_bfloat16*)(ws + 15728640);    //    262,144
    float* zh_w          = (float*)(ws + 15990784);             //    262,144
    __hip_bfloat16* hnew = (__hip_bfloat16*)(ws + 16252928);    // 16,777,216
    // total 33,030,144 bytes

    setup_kernel<<<7040, 256, 0, stream>>>(
        s, a_prev, r_prev, h, Wx, Wh, Wa, xb, wxt, waT, zh_w);
    lstm_gemm<<<dim3(BATCH / 128, HDIM / 32), 256, 0, stream>>>(
        xb, wxt, zh_w, bh, c, hnew);
    head_kernel<<<BATCH / 16, 512, 0, stream>>>(
        hnew, waT, Wv, ba, bv, probs, vout);
}